// Round 5
// baseline (362.814 us; speedup 1.0000x reference)
//
#include <hip/hip_runtime.h>
#include <hip/hip_bf16.h>
#include <hip/hip_fp16.h>
#include <stdint.h>
#include <stddef.h>
#include <string.h>

#define D_EMB 1024
#define SEQ   2048
#define BATCH 4

typedef short bf16x8  __attribute__((ext_vector_type(8)));
typedef short short8  __attribute__((ext_vector_type(8)));
typedef float f32x4   __attribute__((ext_vector_type(4)));

#define AS1 __attribute__((address_space(1)))
#define AS3 __attribute__((address_space(3)))

static __device__ __forceinline__ void async_copy16(const void* g, void* l) {
  __builtin_amdgcn_global_load_lds((const AS1 void*)g, (AS3 void*)l, 16, 0, 0);
}

// ============================================================================
// R5 RESTRUCTURE (R1-R4 schedule variants all flat at ~267 us; the GEMM core
// is kept frozen at the R4-verified form and the ALGORITHM changes instead):
//  (1) weight-space trick: softmax(scale*QK^T) == softmax(scale*(x M x^T
//      + w[k])) with M = Wq Wk^T, w = x (Wk bq)  [row-constant terms cancel
//      in softmax]. Kills the K projection (-17.2 GF) and makes the
//      projection kernel grid 256 blocks = EXACTLY one round (was 384 = 2).
//  (2) pv split-K=2: 256 blocks of 16 k-tiles (was 128/256 blocks x 32 kt),
//      fp32 unsafeAtomicAdd into memset-zeroed out (2 adds/elem: exact).
// R2 LESSON stands: no mid-loop accumulator stores (scratch spill).
// ============================================================================

#define BAR     __builtin_amdgcn_s_barrier()
#define VMCNT6  asm volatile("s_waitcnt vmcnt(6)" ::: "memory")
#define VMCNT0  asm volatile("s_waitcnt vmcnt(0)" ::: "memory")

#define STAGE_A(buf, h, kt) do {                                              \
    const __hip_bfloat16* _g = gA + (size_t)((h) * 128) * lda + ((kt) << 6);  \
    char* _l = (char*)sA + (buf) * 32768 + (h) * 16384 + wave * 1024;         \
    async_copy16(_g, _l);                                                     \
    async_copy16(_g + (size_t)64 * lda, _l + 8192);                           \
  } while (0)
#define STAGE_B(buf, h, kt) do {                                              \
    const __hip_bfloat16* _g = gB + (size_t)((h) * 128) * ldb + ((kt) << 6);  \
    char* _l = (char*)sB + (buf) * 32768 + (h) * 16384 + wave * 1024;         \
    async_copy16(_g, _l);                                                     \
    async_copy16(_g + (size_t)64 * ldb, _l + 8192);                           \
  } while (0)

#define LOAD_A(aF, lbuf, h) do {                                              \
    const __hip_bfloat16* _b = (lbuf) + (wr * 128 + (h) * 64 + lr) * 64;      \
    _Pragma("unroll")                                                         \
    for (int _i = 0; _i < 4; _i++) {                                          \
      aF[_i][0] = *(const bf16x8*)&_b[_i * 1024 + pc0];                       \
      aF[_i][1] = *(const bf16x8*)&_b[_i * 1024 + pc1];                       \
    }                                                                         \
  } while (0)
#define LOAD_B(bF, lbuf, g) do {                                              \
    const __hip_bfloat16* _b = (lbuf) + (wc * 64 + (g) * 32 + lr) * 64;       \
    _Pragma("unroll")                                                         \
    for (int _j = 0; _j < 2; _j++) {                                          \
      bF[_j][0] = *(const bf16x8*)&_b[_j * 1024 + pc0];                       \
      bF[_j][1] = *(const bf16x8*)&_b[_j * 1024 + pc1];                       \
    }                                                                         \
  } while (0)

#define MFMA_Q(aF, bF, h, g) do {                                             \
    __builtin_amdgcn_s_setprio(1);                                            \
    _Pragma("unroll")                                                         \
    for (int _i = 0; _i < 4; _i++)                                            \
      _Pragma("unroll")                                                       \
      for (int _j = 0; _j < 2; _j++) {                                        \
        acc[(h) * 4 + _i][(g) * 2 + _j] =                                     \
          __builtin_amdgcn_mfma_f32_16x16x32_bf16(aF[_i][0], bF[_j][0],       \
              acc[(h) * 4 + _i][(g) * 2 + _j], 0, 0, 0);                      \
        acc[(h) * 4 + _i][(g) * 2 + _j] =                                     \
          __builtin_amdgcn_mfma_f32_16x16x32_bf16(aF[_i][1], bF[_j][1],       \
              acc[(h) * 4 + _i][(g) * 2 + _j], 0, 0, 0);                      \
      }                                                                       \
    __builtin_amdgcn_s_setprio(0);                                            \
  } while (0)

#define ZERO_ACC(acc)                         \
  {                                           \
    f32x4 _z = {0.f, 0.f, 0.f, 0.f};          \
    _Pragma("unroll")                         \
    for (int _i = 0; _i < 8; _i++)            \
      _Pragma("unroll")                       \
      for (int _j = 0; _j < 4; _j++)          \
        acc[_i][_j] = _z;                     \
  }

// ---------------- 256^2-tile 8-phase core (R4-verified, frozen) ----------------
static __device__ __forceinline__ void gemm256(
    const __hip_bfloat16* __restrict__ A, int lda,
    const __hip_bfloat16* __restrict__ Bt, int ldb,
    int K, f32x4 (&acc)[8][4])
{
  __shared__ __hip_bfloat16 sA[2][128 * 64 * 2];   // 64 KiB
  __shared__ __hip_bfloat16 sB[2][128 * 64 * 2];   // 64 KiB

  const int t    = threadIdx.x;   // 0..511
  const int wave = t >> 6;
  const int lane = t & 63;
  const int quad = lane >> 4;
  const int lr   = lane & 15;
  const int wr   = wave >> 2;     // 0..1  (M)
  const int wc   = wave & 3;      // 0..3  (N)

  const int r0 = t >> 3;
  const int cs = (((t & 7) ^ (r0 & 7)) << 3);
  const __hip_bfloat16* gA = A  + (size_t)r0 * lda + cs;
  const __hip_bfloat16* gB = Bt + (size_t)r0 * ldb + cs;

  const int pc0 = ((quad)     ^ (lr & 7)) << 3;
  const int pc1 = ((quad + 4) ^ (lr & 7)) << 3;

  const __hip_bfloat16* const lA0 = sA[0];
  const __hip_bfloat16* const lA1 = sA[1];
  const __hip_bfloat16* const lB0 = sB[0];
  const __hip_bfloat16* const lB1 = sB[1];

  const int nt    = K >> 6;
  const int niter = nt >> 1;

  // prologue: T0 complete (8 copies) + T1 B-lo,B-hi,A-lo (6 in flight).
  STAGE_A(0, 0, 0);
  STAGE_A(0, 1, 0);
  STAGE_B(0, 0, 0);
  STAGE_B(0, 1, 0);
  STAGE_B(1, 0, 1);
  STAGE_B(1, 1, 1);
  STAGE_A(1, 0, 1);
  VMCNT6;
  BAR;

  bf16x8 aF[4][2], bFa[2][2], bFb[2][2];

  for (int j = 0; j < niter - 1; ++j) {
    const int tb = 2 * j + 1, tc = tb + 1, td = tb + 2;

    LOAD_A(aF, lA0, 0); LOAD_B(bFa, lB0, 0);
    STAGE_A(1, 1, tb);
    BAR; MFMA_Q(aF, bFa, 0, 0); BAR;

    LOAD_B(bFb, lB0, 1);
    BAR; MFMA_Q(aF, bFb, 0, 1); BAR;

    LOAD_A(aF, lA0, 1);
    STAGE_B(0, 0, tc);
    BAR; MFMA_Q(aF, bFb, 1, 1); BAR;

    STAGE_B(0, 1, tc);
    STAGE_A(0, 0, tc);
    VMCNT6;
    BAR; MFMA_Q(aF, bFa, 1, 0); BAR;

    LOAD_A(aF, lA1, 0); LOAD_B(bFa, lB1, 0);
    STAGE_A(0, 1, tc);
    BAR; MFMA_Q(aF, bFa, 0, 0); BAR;

    LOAD_B(bFb, lB1, 1);
    BAR; MFMA_Q(aF, bFb, 0, 1); BAR;

    LOAD_A(aF, lA1, 1);
    STAGE_B(1, 0, td);
    BAR; MFMA_Q(aF, bFb, 1, 1); BAR;

    STAGE_B(1, 1, td);
    STAGE_A(1, 0, td);
    VMCNT6;
    BAR; MFMA_Q(aF, bFa, 1, 0); BAR;
  }

  {
    const int tb = nt - 1;
    LOAD_A(aF, lA0, 0); LOAD_B(bFa, lB0, 0);
    STAGE_A(1, 1, tb);
    BAR; MFMA_Q(aF, bFa, 0, 0); BAR;

    LOAD_B(bFb, lB0, 1);
    BAR; MFMA_Q(aF, bFb, 0, 1); BAR;

    LOAD_A(aF, lA0, 1);
    BAR; MFMA_Q(aF, bFb, 1, 1); BAR;

    VMCNT0;
    BAR; MFMA_Q(aF, bFa, 1, 0); BAR;

    LOAD_A(aF, lA1, 0); LOAD_B(bFa, lB1, 0);
    BAR; MFMA_Q(aF, bFa, 0, 0); BAR;

    LOAD_B(bFb, lB1, 1);
    BAR; MFMA_Q(aF, bFb, 0, 1); BAR;

    LOAD_A(aF, lA1, 1);
    BAR; MFMA_Q(aF, bFb, 1, 1); BAR;

    MFMA_Q(aF, bFa, 1, 0);
  }
}

// ---------------- 128^2-tile 2-phase core (R0-verified, for Mt) ----------------
static __device__ __forceinline__ void gemm128(
    const __hip_bfloat16* __restrict__ A, int lda,
    const __hip_bfloat16* __restrict__ Bt, int ldb,
    int K, f32x4 (&acc)[4][4])
{
  __shared__ __hip_bfloat16 ldsA[2][128 * 64];
  __shared__ __hip_bfloat16 ldsB[2][128 * 64];

  const int t    = threadIdx.x;   // 0..255
  const int wave = t >> 6;
  const int lane = t & 63;
  const int quad = lane >> 4;
  const int lr   = lane & 15;
  const int wr   = wave >> 1;
  const int wc   = wave & 1;

  const int r0 = t >> 3;                         // 0..31
  const int c0 = (((t & 7) ^ (r0 & 7)) * 8);     // swizzled source column

  const __hip_bfloat16* gA = A  + (size_t)r0 * lda + c0;
  const __hip_bfloat16* gB = Bt + (size_t)r0 * ldb + c0;

  const int niter = K >> 6;

  {
    char* lA = (char*)ldsA[0] + wave * 1024;
    char* lB = (char*)ldsB[0] + wave * 1024;
#pragma unroll
    for (int ch = 0; ch < 4; ch++) {
      async_copy16(gA + (size_t)(32 * ch) * lda, lA + 4096 * ch);
      async_copy16(gB + (size_t)(32 * ch) * ldb, lB + 4096 * ch);
    }
  }

  int buf = 0;
  for (int it = 0; it < niter; ++it) {
    __syncthreads();

    if (it + 1 < niter) {
      const int k0 = (it + 1) << 6;
      char* lA = (char*)ldsA[buf ^ 1] + wave * 1024;
      char* lB = (char*)ldsB[buf ^ 1] + wave * 1024;
#pragma unroll
      for (int ch = 0; ch < 4; ch++) {
        async_copy16(gA + k0 + (size_t)(32 * ch) * lda, lA + 4096 * ch);
        async_copy16(gB + k0 + (size_t)(32 * ch) * ldb, lB + 4096 * ch);
      }
    }

    const __hip_bfloat16* bA = ldsA[buf];
    const __hip_bfloat16* bB = ldsB[buf];
#pragma unroll
    for (int kk = 0; kk < 64; kk += 32) {
      bf16x8 aF[4], bF[4];
      const int lc = (kk >> 3) + quad;
      const int pc = (lc ^ (lr & 7)) * 8;
#pragma unroll
      for (int i = 0; i < 4; i++)
        aF[i] = *(const bf16x8*)&bA[(wr * 64 + i * 16 + lr) * 64 + pc];
#pragma unroll
      for (int j = 0; j < 4; j++)
        bF[j] = *(const bf16x8*)&bB[(wc * 64 + j * 16 + lr) * 64 + pc];

#pragma unroll
      for (int i = 0; i < 4; i++)
#pragma unroll
        for (int j = 0; j < 4; j++)
          acc[i][j] = __builtin_amdgcn_mfma_f32_16x16x32_bf16(aF[i], bF[j], acc[i][j], 0, 0, 0);
    }
    buf ^= 1;
  }
}

// ---------------- prep: casts + Wv transpose + u = Wk @ bq ----------------
// z=0: Wq->bf16 | z=1: Wk->bf16 | z=2: Wv transpose->Wvt | z=3: x->bf16 | z=4: u
__global__ __launch_bounds__(256) void prep_kernel(
    const float* __restrict__ x,
    const float* __restrict__ Wq,
    const float* __restrict__ Wk,
    const float* __restrict__ Wv,
    const float* __restrict__ bq,
    __hip_bfloat16* __restrict__ xb,
    __hip_bfloat16* __restrict__ Wqb,
    __hip_bfloat16* __restrict__ Wkb,
    __hip_bfloat16* __restrict__ Wvt,
    float* __restrict__ u)
{
  const int tx = threadIdx.x, ty = threadIdx.y;  // (32,8)
  const int tid = ty * 32 + tx;
  const int z = blockIdx.z;
  if (z == 3) {
    const size_t base = ((size_t)blockIdx.y * 32 + blockIdx.x) * 8192;
#pragma unroll
    for (int p = 0; p < 8; p++) {
      const size_t i = base + p * 1024 + tid * 4;
      const float4 v = *(const float4*)(x + i);
      __hip_bfloat16 o[4] = {__float2bfloat16(v.x), __float2bfloat16(v.y),
                             __float2bfloat16(v.z), __float2bfloat16(v.w)};
      *(uint64_t*)(xb + i) = *(uint64_t*)o;
    }
    return;
  }
  if (z < 2) {
    const float* src = (z == 0) ? Wq : Wk;
    __hip_bfloat16* dst = (z == 0) ? Wqb : Wkb;
    const size_t i = ((size_t)blockIdx.y * 32 + blockIdx.x) * 1024 + tid * 4;
    const float4 v = *(const float4*)(src + i);
    __hip_bfloat16 o[4] = {__float2bfloat16(v.x), __float2bfloat16(v.y),
                           __float2bfloat16(v.z), __float2bfloat16(v.w)};
    *(uint64_t*)(dst + i) = *(uint64_t*)o;
    return;
  }
  if (z == 4) {
    // u[d] = sum_e Wk[d,e] * bq[e]   (4 blocks x 256 threads, thread-per-row)
    if (blockIdx.y != 0 || blockIdx.x >= 4) return;
    const int d = blockIdx.x * 256 + tid;
    const float* row = Wk + (size_t)d * D_EMB;
    float s = 0.f;
    for (int e = 0; e < D_EMB; e += 4) {
      const float4 a = *(const float4*)(row + e);
      const float4 b = *(const float4*)(bq + e);
      s += a.x * b.x + a.y * b.y + a.z * b.z + a.w * b.w;
    }
    u[d] = s;
    return;
  }
  // z == 2: transpose Wv
  __shared__ __hip_bfloat16 tile[32][33];
  const int x0 = blockIdx.x * 32;  // e
  const int y0 = blockIdx.y * 32;  // d
#pragma unroll
  for (int i = 0; i < 32; i += 8)
    tile[ty + i][tx] = __float2bfloat16(Wv[(size_t)(y0 + ty + i) * D_EMB + (x0 + tx)]);
  __syncthreads();
#pragma unroll
  for (int i = 0; i < 32; i += 8)
    Wvt[(size_t)(x0 + ty + i) * D_EMB + (y0 + tx)] = tile[tx][ty + i];
}

// ---------------- Mt = Wk @ Wq^T (bf16) and w = xb @ u ----------------
// grid (8, 9): y<8 -> gemm128 tile of Mt ; y==8 -> w rows (8 x 1024 rows).
// Mt[n'][d] = sum_e Wk[n',e] Wq[d,e]  ==> Bt-row n' of the Y GEMM.
__global__ __launch_bounds__(256) void mtw_kernel(
    const __hip_bfloat16* __restrict__ Wkb,
    const __hip_bfloat16* __restrict__ Wqb,
    const __hip_bfloat16* __restrict__ xb,
    const float* __restrict__ u,
    __hip_bfloat16* __restrict__ Mt,
    float* __restrict__ w)
{
  const int t = threadIdx.x;
  if (blockIdx.y == 8) {
    __shared__ float su[1024];
#pragma unroll
    for (int i = 0; i < 4; i++) su[t + 256 * i] = u[t + 256 * i];
    __syncthreads();
    const int s0 = blockIdx.x * 1024;
#pragma unroll
    for (int rr = 0; rr < 4; rr++) {
      const int s = s0 + rr * 256 + t;
      const __hip_bfloat16* row = xb + (size_t)s * D_EMB;
      float sum = 0.f;
      for (int e = 0; e < D_EMB; e += 8) {
        const short8 v = *(const short8*)(row + e);
#pragma unroll
        for (int i = 0; i < 8; i++) {
          __hip_bfloat16 hb; const short sv = v[i]; memcpy(&hb, &sv, 2);
          sum += __bfloat162float(hb) * su[e + i];
        }
      }
      w[s] = sum;
    }
    return;
  }
  const int m0 = blockIdx.x * 128;
  const int n0 = blockIdx.y * 128;
  f32x4 acc[4][4];
  {
    f32x4 z4 = {0.f, 0.f, 0.f, 0.f};
#pragma unroll
    for (int i = 0; i < 4; i++)
#pragma unroll
      for (int j = 0; j < 4; j++) acc[i][j] = z4;
  }
  gemm128(Wkb + (size_t)m0 * D_EMB, D_EMB,
          Wqb + (size_t)n0 * D_EMB, D_EMB, D_EMB, acc);

  const int wave = t >> 6, lane = t & 63;
  const int quad = lane >> 4, lr = lane & 15;
  const int wr = wave >> 1, wc = wave & 1;
#pragma unroll
  for (int i = 0; i < 4; i++)
#pragma unroll
    for (int j = 0; j < 4; j++) {
      const int n = n0 + wc * 64 + j * 16 + lr;
      const int mb = m0 + wr * 64 + i * 16 + quad * 4;
#pragma unroll
      for (int r = 0; r < 4; r++)
        Mt[(size_t)(mb + r) * D_EMB + n] = __float2bfloat16(acc[i][j][r]);
    }
}

// ---------------- projections: z=0 -> Y = xb @ Mt^T ; z=1 -> V -> Vt ----------------
// grid (32, 4, 2) = 256 blocks = exactly one occupancy round.
__global__ __launch_bounds__(512, 2) void qkv_kernel(
    const __hip_bfloat16* __restrict__ xb,
    const __hip_bfloat16* __restrict__ Mt,
    const __hip_bfloat16* __restrict__ Wvt,
    const float* __restrict__ bv,
    __hip_bfloat16* __restrict__ Y,
    __hip_bfloat16* __restrict__ Vt)
{
  const int mat = blockIdx.z;
  const int m0  = blockIdx.x * 256;
  const int n0  = blockIdx.y * 256;

  f32x4 acc[8][4];
  ZERO_ACC(acc);

  const __hip_bfloat16* Bt = (mat == 0) ? Mt : Wvt;
  gemm256(xb + (size_t)m0 * D_EMB, D_EMB,
          Bt + (size_t)n0 * D_EMB, D_EMB, D_EMB, acc);

  const int t = threadIdx.x;
  const int wave = t >> 6, lane = t & 63;
  const int quad = lane >> 4, lr = lane & 15;
  const int wr = wave >> 2, wc = wave & 3;

#pragma unroll
  for (int i = 0; i < 8; i++) {
#pragma unroll
    for (int j = 0; j < 4; j++) {
      const int n = n0 + wc * 64 + j * 16 + lr;
      const int mbase = m0 + wr * 128 + i * 16 + quad * 4;
      if (mat == 1) {
        const float bb = bv[n];
        const int b = mbase >> 11, s = mbase & 2047;
        __hip_bfloat16 pk[4];
#pragma unroll
        for (int r = 0; r < 4; r++) pk[r] = __float2bfloat16(acc[i][j][r] + bb);
        *(uint64_t*)&Vt[(size_t)b * D_EMB * SEQ + (size_t)n * SEQ + s] = *(uint64_t*)pk;
      } else {
#pragma unroll
        for (int r = 0; r < 4; r++)
          Y[(size_t)(mbase + r) * D_EMB + n] = __float2bfloat16(acc[i][j][r]);
      }
    }
  }
}

// ---------------- scores = scale*(Y @ xb^T + w[k]) (fp16 out) ----------------
__global__ __launch_bounds__(512, 2) void scores_kernel(
    const __hip_bfloat16* __restrict__ Y,
    const __hip_bfloat16* __restrict__ xb,
    const float* __restrict__ w,
    __half* __restrict__ Sc)
{
  const int b  = blockIdx.z;
  const int m0 = blockIdx.y * 256;  // s_q
  const int n0 = blockIdx.x * 256;  // s_k

  f32x4 acc[8][4];
  ZERO_ACC(acc);

  gemm256(Y  + ((size_t)b * SEQ + m0) * D_EMB, D_EMB,
          xb + ((size_t)b * SEQ + n0) * D_EMB, D_EMB,
          D_EMB, acc);

  __half* out = Sc + (size_t)b * SEQ * SEQ;
  const float scale = 0.03125f;  // 1/sqrt(1024)

  const int t = threadIdx.x;
  const int wave = t >> 6, lane = t & 63;
  const int quad = lane >> 4, lr = lane & 15;
  const int wr = wave >> 2, wc = wave & 3;

#pragma unroll
  for (int i = 0; i < 8; i++)
#pragma unroll
    for (int j = 0; j < 4; j++) {
      const int n = n0 + wc * 64 + j * 16 + lr;
      const float wv = w[(size_t)b * SEQ + n];
#pragma unroll
      for (int r = 0; r < 4; r++) {
        const int m = m0 + wr * 128 + i * 16 + quad * 4 + r;
        out[(size_t)m * SEQ + n] = __float2half((acc[i][j][r] + wv) * scale);
      }
    }
}

// ---------------- row softmax: fp16 scores -> bf16 probs ----------------
__global__ __launch_bounds__(256) void softmax_kernel(
    const __half* __restrict__ Sc, __hip_bfloat16* __restrict__ P)
{
  const int row = blockIdx.x;  // 0..8191
  const __half* src = Sc + (size_t)row * SEQ;
  const int t = threadIdx.x;
  const int wave = t >> 6, lane = t & 63;

  const short8 raw = *(const short8*)(src + t * 8);
  float v[8];
#pragma unroll
  for (int i = 0; i < 8; i++) {
    const short si = raw[i];
    __half h;
    memcpy(&h, &si, sizeof(h));
    v[i] = __half2float(h);
  }

  float m = v[0];
#pragma unroll
  for (int i = 1; i < 8; i++) m = fmaxf(m, v[i]);
#pragma unroll
  for (int o = 32; o > 0; o >>= 1) m = fmaxf(m, __shfl_xor(m, o));

  __shared__ float redm[4];
  __shared__ float reds[4];
  if (lane == 0) redm[wave] = m;
  __syncthreads();
  m = fmaxf(fmaxf(redm[0], redm[1]), fmaxf(redm[2], redm[3]));

  float e[8], s = 0.f;
#pragma unroll
  for (int i = 0; i < 8; i++) { e[i] = __expf(v[i] - m); s += e[i]; }
#pragma unroll
  for (int o = 32; o > 0; o >>= 1) s += __shfl_xor(s, o);
  if (lane == 0) reds[wave] = s;
  __syncthreads();
  s = reds[0] + reds[1] + reds[2] + reds[3];

  const float inv = 1.f / s;
  short8 outp;
#pragma unroll
  for (int i = 0; i < 8; i++) {
    const __hip_bfloat16 b = __float2bfloat16(e[i] * inv);
    short sb;
    memcpy(&sb, &b, sizeof(sb));
    outp[i] = sb;
  }
  *(short8*)(P + (size_t)row * SEQ + t * 8) = outp;
}

// ---------------- out += P @ V  (split-K=2, fp32 atomics, out pre-zeroed) ----------------
// grid (8, 8, 4): x = n-tile(0..3) | k-half(0..1)<<2 ; 256 blocks, 16 kt each.
__global__ __launch_bounds__(512, 2) void pv_kernel(
    const __hip_bfloat16* __restrict__ P,
    const __hip_bfloat16* __restrict__ Vt,
    float* __restrict__ out)
{
  const int b  = blockIdx.z;
  const int m0 = blockIdx.y * 256;           // s_q
  const int n0 = (blockIdx.x & 3) * 256;     // e
  const int kh = (blockIdx.x >> 2) * 1024;   // k-half offset

  f32x4 acc[8][4];
  ZERO_ACC(acc);

  gemm256(P  + (size_t)b * SEQ * SEQ   + (size_t)m0 * SEQ + kh, SEQ,
          Vt + (size_t)b * D_EMB * SEQ + (size_t)n0 * SEQ + kh, SEQ,
          1024, acc);

  float* o = out + (size_t)b * SEQ * D_EMB;

  const int t = threadIdx.x;
  const int wave = t >> 6, lane = t & 63;
  const int quad = lane >> 4, lr = lane & 15;
  const int wr = wave >> 2, wc = wave & 3;

#pragma unroll
  for (int i = 0; i < 8; i++)
#pragma unroll
    for (int j = 0; j < 4; j++) {
      const int n = n0 + wc * 64 + j * 16 + lr;
#pragma unroll
      for (int r = 0; r < 4; r++) {
        const int m = m0 + wr * 128 + i * 16 + quad * 4 + r;
        unsafeAtomicAdd(&o[(size_t)m * D_EMB + n], acc[i][j][r]);
      }
    }
}

extern "C" void kernel_launch(void* const* d_in, const int* in_sizes, int n_in,
                              void* d_out, int out_size, void* d_ws, size_t ws_size,
                              hipStream_t stream) {
  const float* x  = (const float*)d_in[0];
  const float* Wq = (const float*)d_in[1];
  const float* bq = (const float*)d_in[2];
  const float* Wk = (const float*)d_in[3];
  const float* bk = (const float*)d_in[4];
  const float* bv = (const float*)d_in[6];
  const float* Wv = (const float*)d_in[5];
  (void)bk;  // bk-dependent terms are per-row constants: cancel in softmax
  float* out = (float*)d_out;

  char* ws = (char*)d_ws;
  __hip_bfloat16* xb  = (__hip_bfloat16*)(ws);                // 16,777,216
  __hip_bfloat16* Wqb = (__hip_bfloat16*)(ws + 16777216);     //  2,097,152
  __hip_bfloat16* Wkb = (__hip_bfloat16*)(ws + 18874368);     //  2,097,152
  __hip_bfloat16* Wvt = (__hip_bfloat16*)(ws + 20971520);     //  2,097,152
  __hip_bfloat16* Mt  = (__hip_bfloat16*)(ws + 23068672);     //  2,097,152
  float*          u   = (float*)         (ws + 25165824);     //      4,096
  float*          w   = (float*)         (ws + 25169920);     //     32,768
  __hip_bfloat16* Y   = (__hip_bfloat16*)(ws + 25202688);     // 16,777,216
  __hip_bfloat16* Vt  = (__hip_bfloat16*)(ws + 41979904);     // 16,777,216
  __half*         Sc  = (__half*)        (ws + 58757120);     // 33,554,432
  __hip_bfloat16* P   = (__hip_bfloat16*)(ws + 92311552);     // 33,554,432
  // total 125,865,984 bytes (< previous 174 MB footprint)

  hipMemsetAsync(out, 0, (size_t)BATCH * SEQ * D_EMB * 4, stream);
  prep_kernel  <<<dim3(32, 32, 5), dim3(32, 8), 0, stream>>>(x, Wq, Wk, Wv, bq,
                                                             xb, Wqb, Wkb, Wvt, u);
  mtw_kernel   <<<dim3(8, 9),      256,        0, stream>>>(Wkb, Wqb, xb, u, Mt, w);
  qkv_kernel   <<<dim3(32, 4, 2),  512,        0, stream>>>(xb, Mt, Wvt, bv, Y, Vt);
  scores_kernel<<<dim3(8, 8, 4),   512,        0, stream>>>(Y, xb, w, Sc);
  softmax_kernel<<<dim3(8192),     256,        0, stream>>>(Sc, P);
  pv_kernel    <<<dim3(8, 8, 4),   512,        0, stream>>>(P, Vt, out);
}